// Round 1
// baseline (19928.766 us; speedup 1.0000x reference)
//
#include <hip/hip_runtime.h>

// ---------------------------------------------------------------------------
// NeuralODE RK4:  y' = f(y),  f = tanh(BN2(relu(BN1(relu(y W1+b1)) W2+b2)) Wo+bo)
// BN (inference) folded:  W2' = diag(s1)W2, b2' = b2 + t1@W2  (s=g*rsqrt(v+eps),
// t = be - s*m); same for Wo.  f(y) = tanh(relu(relu(y W1+b1) W2'+b2') Wo'+bo').
//
// Precision: bf16 hi/lo split GEMM as a single K=768 contraction:
//   A' cols: [0,256)=Ah  [256,512)=Al  [512,768)=Ah(re-read)
//   B' rows: [0,256)=Bh  [256,512)=Bh  [512,768)=Bl
//   => Ah@Bh + Al@Bh + Ah@Bl  (~2^-17 rel error, f32-equivalent for this net)
// LDS act buffer stores only [Ah|Al] (K=512); the third K-range re-reads Ah.
// ---------------------------------------------------------------------------

typedef unsigned short u16;
typedef unsigned int   u32;
typedef __attribute__((ext_vector_type(8))) short bf16x8;  // 8 bf16 in 4 VGPRs
typedef __attribute__((ext_vector_type(4))) float f32x4;

#define BN_EPS 1e-3f
#define NROWS  65536
#define BM     128          // rows per block
#define NTHR   512          // 8 waves: 2 (row) x 4 (col)
#define WT_ELEMS 196608     // 768*256 per layer

__device__ __forceinline__ u16 f2bf(float f) {         // RNE f32 -> bf16 bits
    u32 u = __float_as_uint(f);
    u32 r = u + 0x7FFFu + ((u >> 16) & 1u);
    return (u16)(r >> 16);
}
__device__ __forceinline__ float bf2f(u16 h) {
    return __uint_as_float(((u32)h) << 16);
}
__device__ __forceinline__ float fast_tanh(float x) {
    // tanh(x) = 1 - 2/(e^{2x}+1); exact at +-inf, ~1e-6 abs error
    float e = __expf(2.0f * x);
    return 1.0f - __fdividef(2.0f, e + 1.0f);
}

// LDS act tile [128 rows][512 bf16], row stride 1KiB.
// XOR swizzle on k-byte bits 4..6 breaks the 16-way bank conflict of the
// stride-1KiB column read (G4); involution, 16B-chunk-preserving.
#define SWZ(row, kb) (((row) << 10) + ((kb) ^ (((row) & 7) << 4)))

// ---------------------------------------------------------------------------
// prep: fold BN into biases
__global__ void prep_bias(const float* __restrict__ b2,
                          const float* __restrict__ g1, const float* __restrict__ be1,
                          const float* __restrict__ m1, const float* __restrict__ v1,
                          const float* __restrict__ W2,
                          const float* __restrict__ bo,
                          const float* __restrict__ g2, const float* __restrict__ be2,
                          const float* __restrict__ m2, const float* __restrict__ v2,
                          const float* __restrict__ Wo,
                          float* __restrict__ b2o, float* __restrict__ boo) {
    int t = threadIdx.x;
    if (t < 256) {
        float s = b2[t];
        for (int i = 0; i < 256; ++i) {
            float s1 = g1[i] * rsqrtf(v1[i] + BN_EPS);
            float t1 = be1[i] - s1 * m1[i];
            s += t1 * W2[i * 256 + t];
        }
        b2o[t] = s;
    } else {
        int j = t - 256;
        float s = bo[j];
        for (int i = 0; i < 256; ++i) {
            float s2 = g2[i] * rsqrtf(v2[i] + BN_EPS);
            float t2 = be2[i] - s2 * m2[i];
            s += t2 * Wo[i * 256 + j];
        }
        boo[j] = s;
    }
}

// prep: scale + split + frag-linear-swizzle weights.
// Dest layout per layer (element idx): (ks*16+cb)*512 + c*32 + g*8 + j
//   ks=k'>>5, g=(k'>>3)&3, j=k'&7, cb=col>>4, c=col&15
// so a wave's 4 B-frag dwordx4 loads are each 1KiB fully-coalesced.
__global__ void prep_weights(const float* __restrict__ W1, const float* __restrict__ W2,
                             const float* __restrict__ Wo,
                             const float* __restrict__ g1, const float* __restrict__ v1,
                             const float* __restrict__ g2, const float* __restrict__ v2,
                             u16* __restrict__ Wt) {
    int tid = blockIdx.x * 256 + threadIdx.x;
    if (tid >= 3 * 768 * 256) return;
    int l   = tid / (768 * 256);
    int r   = tid % (768 * 256);
    int kp  = r >> 8;          // 0..767 (k' of the extended contraction)
    int col = r & 255;
    int ok  = kp & 255;        // original k
    float w;
    if (l == 0)      w = W1[ok * 256 + col];
    else if (l == 1) w = W2[ok * 256 + col] * (g1[ok] * rsqrtf(v1[ok] + BN_EPS));
    else             w = Wo[ok * 256 + col] * (g2[ok] * rsqrtf(v2[ok] + BN_EPS));
    u16 hi = f2bf(w);
    u16 out = (kp < 512) ? hi : f2bf(w - bf2f(hi));   // rows [0,512)=Bh, [512,768)=Bl
    int ks = kp >> 5, gg = (kp >> 3) & 3, j = kp & 7, cb = col >> 4, cc = col & 15;
    Wt[(size_t)l * WT_ELEMS + ks * 8192 + cb * 512 + cc * 32 + gg * 8 + j] = out;
}

// ---------------------------------------------------------------------------
// Fused f-eval.  MODE 0: k=f(y),          kbuf=k, acc =w*k
//                MODE 1: k=f(y+c*kprev),  kbuf=k, acc+=w*k
//                MODE 2: k=f(y+c*kprev),  y += acc + w*k   (stage 4)
// In-place hazards are safe: every block only touches its own 128 rows.
template<int MODE>
__global__ __launch_bounds__(NTHR, 2)
void eval_kernel(float* __restrict__ y, float* __restrict__ kbuf, float* __restrict__ acc,
                 const u16* __restrict__ Wt,
                 const float* __restrict__ bias0, const float* __restrict__ bias1,
                 const float* __restrict__ bias2,
                 float c_in, float w_acc) {
    extern __shared__ char smem[];
    const int t = threadIdx.x;
    const size_t rowbase = (size_t)blockIdx.x * BM;

    // ---- prologue: x = y (+ c*kprev); split hi/lo into LDS act tile ----
    {
        const int r  = t >> 2;                 // 0..127
        const int fc = t & 3;                  // 4 threads per row
        const float4* yp = reinterpret_cast<const float4*>(y)    + (rowbase + r) * 64;
        const float4* kp = reinterpret_cast<const float4*>(kbuf) + (rowbase + r) * 64;
#pragma unroll 4
        for (int q = 0; q < 16; ++q) {
            const int fi = fc + (q << 2);      // float4 index in row (0..63)
            float4 v = yp[fi];
            if (MODE != 0) {
                const float4 kv = kp[fi];
                v.x = fmaf(c_in, kv.x, v.x);
                v.y = fmaf(c_in, kv.y, v.y);
                v.z = fmaf(c_in, kv.z, v.z);
                v.w = fmaf(c_in, kv.w, v.w);
            }
            ushort4 hi, lo;
            hi.x = f2bf(v.x); lo.x = f2bf(v.x - bf2f(hi.x));
            hi.y = f2bf(v.y); lo.y = f2bf(v.y - bf2f(hi.y));
            hi.z = f2bf(v.z); lo.z = f2bf(v.z - bf2f(hi.z));
            hi.w = f2bf(v.w); lo.w = f2bf(v.w - bf2f(hi.w));
            *reinterpret_cast<ushort4*>(smem + SWZ(r, fi * 8))       = hi;
            *reinterpret_cast<ushort4*>(smem + SWZ(r, 512 + fi * 8)) = lo;
        }
    }
    __syncthreads();

    const int lane = t & 63;
    const int wid  = t >> 6;
    const int wr   = wid >> 2;    // 0..1 : 64-row group
    const int wc   = wid & 3;     // 0..3 : 64-col group
    const int c16  = lane & 15;
    const int g    = lane >> 4;   // 0..3

    f32x4 accf[4][4];

#pragma unroll
    for (int l = 0; l < 3; ++l) {
        const u16* __restrict__ wt = Wt + (size_t)l * WT_ELEMS;
        const float* bp = (l == 0) ? bias0 : (l == 1) ? bias1 : bias2;

        // acc init = bias (per output column)
#pragma unroll
        for (int n = 0; n < 4; ++n) {
            const float bv = bp[wc * 64 + n * 16 + c16];
#pragma unroll
            for (int m = 0; m < 4; ++m) accf[m][n] = {bv, bv, bv, bv};
        }

        // K loop over 768 = [Ah|Al|Ah] x [Bh|Bh|Bl]
#pragma unroll 2
        for (int ks = 0; ks < 24; ++ks) {
            const int kfull = ks * 32;
            const int kloc  = (kfull >= 512) ? (kfull - 512) : kfull;  // LDS re-reads Ah
            const int kb    = kloc * 2 + g * 16;
            bf16x8 av[4], bv[4];
#pragma unroll
            for (int m = 0; m < 4; ++m) {
                const int row = wr * 64 + m * 16 + c16;
                av[m] = *reinterpret_cast<const bf16x8*>(smem + SWZ(row, kb));
            }
            const u16* wp = wt + (size_t)(ks * 16 + wc * 4) * 512 + c16 * 32 + g * 8;
#pragma unroll
            for (int n = 0; n < 4; ++n)
                bv[n] = *reinterpret_cast<const bf16x8*>(wp + n * 512);
#pragma unroll
            for (int m = 0; m < 4; ++m)
#pragma unroll
                for (int n = 0; n < 4; ++n)
                    accf[m][n] = __builtin_amdgcn_mfma_f32_16x16x32_bf16(
                        av[m], bv[n], accf[m][n], 0, 0, 0);
        }
        __syncthreads();   // all act reads done before overwrite / exit

        if (l < 2) {
            // relu -> hi/lo split -> same LDS tile (it is the next layer's A)
#pragma unroll
            for (int m = 0; m < 4; ++m)
#pragma unroll
                for (int n = 0; n < 4; ++n) {
                    const int col = wc * 64 + n * 16 + c16;
#pragma unroll
                    for (int j = 0; j < 4; ++j) {
                        const int row = wr * 64 + m * 16 + g * 4 + j;  // C layout (m89)
                        const float h = fmaxf(accf[m][n][j], 0.0f);
                        const u16 hi = f2bf(h);
                        const u16 lo = f2bf(h - bf2f(hi));
                        *reinterpret_cast<u16*>(smem + SWZ(row, col * 2))       = hi;
                        *reinterpret_cast<u16*>(smem + SWZ(row, 512 + col * 2)) = lo;
                    }
                }
            __syncthreads();
        } else {
            // output epilogue: tanh + RK4 bookkeeping
#pragma unroll
            for (int m = 0; m < 4; ++m)
#pragma unroll
                for (int n = 0; n < 4; ++n) {
                    const int col = wc * 64 + n * 16 + c16;
#pragma unroll
                    for (int j = 0; j < 4; ++j) {
                        const int row = wr * 64 + m * 16 + g * 4 + j;
                        const size_t gi = (rowbase + row) * 256 + col;
                        const float kv = fast_tanh(accf[m][n][j]);
                        if (MODE == 0)      { kbuf[gi] = kv; acc[gi] = w_acc * kv; }
                        else if (MODE == 1) { kbuf[gi] = kv; acc[gi] += w_acc * kv; }
                        else                { y[gi] = y[gi] + acc[gi] + w_acc * kv; }
                    }
                }
        }
    }
}

// ---------------------------------------------------------------------------
extern "C" void kernel_launch(void* const* d_in, const int* in_sizes, int n_in,
                              void* d_out, int out_size, void* d_ws, size_t ws_size,
                              hipStream_t stream) {
    const float* y0  = (const float*)d_in[0];
    const float* W1  = (const float*)d_in[1];
    const float* b1  = (const float*)d_in[2];
    const float* g1  = (const float*)d_in[3];
    const float* be1 = (const float*)d_in[4];
    const float* m1  = (const float*)d_in[5];
    const float* v1  = (const float*)d_in[6];
    const float* W2  = (const float*)d_in[7];
    const float* b2  = (const float*)d_in[8];
    const float* g2  = (const float*)d_in[9];
    const float* be2 = (const float*)d_in[10];
    const float* m2  = (const float*)d_in[11];
    const float* v2  = (const float*)d_in[12];
    const float* Wo  = (const float*)d_in[13];
    const float* bo  = (const float*)d_in[14];

    float* y = (float*)d_out;                                  // state lives in d_out
    char*  ws = (char*)d_ws;
    const size_t MB = 1024 * 1024;
    float* kbuf = (float*)(ws);                                // 64 MB
    float* accb = (float*)(ws + 64 * MB);                      // 64 MB
    u16*   Wt   = (u16*)  (ws + 128 * MB);                     // 3*384 KB
    float* b2o  = (float*)(ws + 130 * MB);
    float* boo  = b2o + 256;

    // allow 128 KiB dynamic LDS (idempotent host-side calls; capture-safe)
    hipFuncSetAttribute(reinterpret_cast<const void*>(&eval_kernel<0>),
                        hipFuncAttributeMaxDynamicSharedMemorySize, 131072);
    hipFuncSetAttribute(reinterpret_cast<const void*>(&eval_kernel<1>),
                        hipFuncAttributeMaxDynamicSharedMemorySize, 131072);
    hipFuncSetAttribute(reinterpret_cast<const void*>(&eval_kernel<2>),
                        hipFuncAttributeMaxDynamicSharedMemorySize, 131072);

    hipMemcpyAsync(y, y0, (size_t)NROWS * 256 * sizeof(float),
                   hipMemcpyDeviceToDevice, stream);
    prep_bias<<<1, 512, 0, stream>>>(b2, g1, be1, m1, v1, W2,
                                     bo, g2, be2, m2, v2, Wo, b2o, boo);
    prep_weights<<<2304, 256, 0, stream>>>(W1, W2, Wo, g1, v1, g2, v2, Wt);

    const float dt = 1.0f / 40.0f;
    const float c2 = 0.5f * dt, c4 = dt;
    const float w16 = dt / 6.0f, w13 = dt / 3.0f;
    const int grid = NROWS / BM;   // 512

    for (int s = 0; s < 40; ++s) {
        eval_kernel<0><<<grid, NTHR, 131072, stream>>>(y, kbuf, accb, Wt, b1, b2o, boo, 0.0f, w16);
        eval_kernel<1><<<grid, NTHR, 131072, stream>>>(y, kbuf, accb, Wt, b1, b2o, boo, c2, w13);
        eval_kernel<1><<<grid, NTHR, 131072, stream>>>(y, kbuf, accb, Wt, b1, b2o, boo, c2, w13);
        eval_kernel<2><<<grid, NTHR, 131072, stream>>>(y, kbuf, accb, Wt, b1, b2o, boo, c4, w16);
    }
}